// Round 11
// baseline (576.787 us; speedup 1.0000x reference)
//
#include <hip/hip_runtime.h>

#define DIM 256
#define SCAN_B 256

typedef __attribute__((ext_vector_type(8))) short short8;
typedef __attribute__((ext_vector_type(8))) unsigned short u16x8;
typedef __attribute__((ext_vector_type(4))) float f32x4;

__device__ __forceinline__ unsigned short f32_to_bf16(float x) {
    unsigned int u = __float_as_uint(x);
    unsigned int r = u + 0x7FFFu + ((u >> 16) & 1u);
    return (unsigned short)(r >> 16);
}
__device__ __forceinline__ float bf16_to_f32(unsigned short h) {
    return __uint_as_float(((unsigned int)h) << 16);
}

// ---------------- degree histogram ----------------
__global__ void deg_kernel(const int* __restrict__ dst, int E, int* __restrict__ deg) {
    int e = blockIdx.x * blockDim.x + threadIdx.x;
    if (e < E) atomicAdd(&deg[dst[e]], 1);
}

// ---------------- hierarchical exclusive scan (deg -> row_start) ----------------
__global__ void scan1_kernel(const int* __restrict__ deg, int N,
                             int* __restrict__ excl, int* __restrict__ bsums) {
    __shared__ int s[SCAN_B];
    int tid = threadIdx.x;
    int i = blockIdx.x * SCAN_B + tid;
    int v = (i < N) ? deg[i] : 0;
    s[tid] = v;
    __syncthreads();
    #pragma unroll
    for (int off = 1; off < SCAN_B; off <<= 1) {
        int t = (tid >= off) ? s[tid - off] : 0;
        __syncthreads();
        s[tid] += t;
        __syncthreads();
    }
    if (i <= N) excl[i] = s[tid] - v;
    if (tid == SCAN_B - 1) bsums[blockIdx.x] = s[tid];
}

__global__ void scan2_kernel(int* __restrict__ bsums, int nb) {
    __shared__ int s[SCAN_B];
    int tid = threadIdx.x;
    int v = (tid < nb) ? bsums[tid] : 0;
    s[tid] = v;
    __syncthreads();
    #pragma unroll
    for (int off = 1; off < SCAN_B; off <<= 1) {
        int t = (tid >= off) ? s[tid - off] : 0;
        __syncthreads();
        s[tid] += t;
        __syncthreads();
    }
    if (tid < nb) bsums[tid] = s[tid] - v;
}

// scan3 + inv_deg fused
__global__ void scan3_kernel(const int* __restrict__ excl, const int* __restrict__ bsums,
                             const int* __restrict__ deg, int N,
                             int* __restrict__ row_start, float* __restrict__ inv_deg) {
    int i = blockIdx.x * SCAN_B + threadIdx.x;
    if (i <= N) row_start[i] = excl[i] + bsums[blockIdx.x];
    if (i < N) inv_deg[i] = 1.0f / (float)max(deg[i], 1);
}

// ---------------- CSR bucket fill ----------------
__global__ void fill_kernel(const int* __restrict__ src, const int* __restrict__ dst, int E,
                            const int* __restrict__ row_start, int* __restrict__ cursor,
                            int* __restrict__ csr_src) {
    int e = blockIdx.x * blockDim.x + threadIdx.x;
    if (e < E) {
        int d = dst[e];
        int pos = row_start[d] + atomicAdd(&cursor[d], 1);
        csr_src[pos] = src[e];
    }
}

// ---------------- combined prep: W -> bf16 transpose, x0 -> bf16 ----------------
__global__ void prep_kernel(const float* __restrict__ W, unsigned short* __restrict__ Wt,
                            const float* __restrict__ x0, unsigned short* __restrict__ x0b,
                            int n4) {
    int b = blockIdx.x;
    if (b < DIM) {
        int k = b, n = threadIdx.x;
        Wt[n * DIM + k] = f32_to_bf16(W[k * DIM + n]);
    } else {
        int i = (b - DIM) * 256 + threadIdx.x;
        if (i < n4) {
            float4 v = ((const float4*)x0)[i];
            ushort4 o;
            o.x = f32_to_bf16(v.x); o.y = f32_to_bf16(v.y);
            o.z = f32_to_bf16(v.z); o.w = f32_to_bf16(v.w);
            ((ushort4*)x0b)[i] = o;
        }
    }
}

// ---------------- fused layer: gather+mix -> LDS (plane layout) -> MFMA -> relu ----
// 64-node tile, 256 threads, As 32 KB -> 5 blocks/CU.
// LDS h layout (R6-verified): element k of row r at As[(k>>5)*2048 + r*32 + (k&31)].
// Gather (R10-verified): lane owns 8 cols; wave halves process 2 edges concurrently.
// Phase 2 (R6-verified): A frags from LDS planes, B frags per-lane from plain Wt.
template <bool LAST>
__global__ __launch_bounds__(256) void layer_kernel(
    const unsigned short* __restrict__ act_in, const unsigned short* __restrict__ x0b,
    const int* __restrict__ row_start, const int* __restrict__ csr_src,
    const float* __restrict__ inv_deg, const unsigned short* __restrict__ Wt,
    float* __restrict__ out_f32, unsigned short* __restrict__ out_bf16, int N)
{
    __shared__ unsigned short As[8 * 64 * 32];  // 32 KB

    const int t    = threadIdx.x;
    const int w    = t >> 6;
    const int lane = t & 63;
    const int lm   = lane & 15;
    const int q    = lane >> 4;
    const int m0   = blockIdx.x * 64;
    const int half = lane >> 5;
    const int c    = (lane & 31) * 8;   // 8-column base
    const int ckb  = c >> 5;            // plane
    const int cko  = c & 31;            // offset within plane row

    // ---- phase 1: gather + residual mix -> bf16 h rows in LDS planes ----
    #pragma unroll 1
    for (int i = 0; i < 16; i++) {
        int r = i * 4 + w;              // wave-interleaved rows
        int node = m0 + r;
        if (node >= N) continue;        // wave-uniform branch
        int beg = row_start[node];
        int end = row_start[node + 1];

        float a[8];
        #pragma unroll
        for (int j = 0; j < 8; j++) a[j] = 0.f;

        int e = beg;
        for (; e + 4 <= end; e += 4) {          // 4 edges/iter (2 per half)
            int s0 = csr_src[e + half];
            int s1 = csr_src[e + 2 + half];
            u16x8 v0 = *(const u16x8*)(act_in + (size_t)s0 * DIM + c);
            u16x8 v1 = *(const u16x8*)(act_in + (size_t)s1 * DIM + c);
            #pragma unroll
            for (int j = 0; j < 8; j++) a[j] += bf16_to_f32(v0[j]) + bf16_to_f32(v1[j]);
        }
        if (e + 2 <= end) {                     // 2-edge remainder
            int s0 = csr_src[e + half];
            u16x8 v0 = *(const u16x8*)(act_in + (size_t)s0 * DIM + c);
            #pragma unroll
            for (int j = 0; j < 8; j++) a[j] += bf16_to_f32(v0[j]);
            e += 2;
        }
        if (e < end && half == 0) {             // odd tail: lo half only
            int s0 = csr_src[e];
            u16x8 v0 = *(const u16x8*)(act_in + (size_t)s0 * DIM + c);
            #pragma unroll
            for (int j = 0; j < 8; j++) a[j] += bf16_to_f32(v0[j]);
        }

        #pragma unroll
        for (int j = 0; j < 8; j++) a[j] += __shfl_xor(a[j], 32);

        if (half == 0) {
            float scale = 0.9f * inv_deg[node];
            u16x8 xv = *(const u16x8*)(x0b + (size_t)node * DIM + c);
            u16x8 o;
            #pragma unroll
            for (int j = 0; j < 8; j++)
                o[j] = f32_to_bf16(0.1f * bf16_to_f32(xv[j]) + scale * a[j]);
            *(u16x8*)&As[ckb * 2048 + r * 32 + cko] = o;
        }
    }
    __syncthreads();

    // ---- phase 2: barrier-free MFMA K-loop ----
    f32x4 acc[4][4];
    #pragma unroll
    for (int mi = 0; mi < 4; mi++)
        #pragma unroll
        for (int ni = 0; ni < 4; ni++)
            acc[mi][ni] = (f32x4){0.f, 0.f, 0.f, 0.f};

    #pragma unroll 1
    for (int kb = 0; kb < 8; kb++) {
        short8 b[4];
        #pragma unroll
        for (int ni = 0; ni < 4; ni++) {
            int n = w * 64 + ni * 16 + lm;                 // output column
            b[ni] = *(const short8*)(Wt + (size_t)n * DIM + kb * 32 + q * 8);
        }
        short8 a[4];
        #pragma unroll
        for (int mi = 0; mi < 4; mi++)
            a[mi] = *(const short8*)&As[kb * 2048 + (mi * 16 + lm) * 32 + q * 8];
        #pragma unroll
        for (int ni = 0; ni < 4; ni++) {
            #pragma unroll
            for (int mi = 0; mi < 4; mi++)
                acc[mi][ni] = __builtin_amdgcn_mfma_f32_16x16x32_bf16(a[mi], b[ni], acc[mi][ni], 0, 0, 0);
        }
    }

    // ---- epilogue: C/D layout col=lane&15, row=q*4+reg (R4/R6-verified) ----
    #pragma unroll
    for (int mi = 0; mi < 4; mi++) {
        const int rowb = m0 + mi * 16 + q * 4;
        #pragma unroll
        for (int ni = 0; ni < 4; ni++) {
            const int col = w * 64 + ni * 16 + lm;
            #pragma unroll
            for (int r4 = 0; r4 < 4; r4++) {
                int row = rowb + r4;
                if (row < N) {
                    float v = fmaxf(acc[mi][ni][r4], 0.0f);
                    if (LAST) out_f32[(size_t)row * DIM + col] = v;
                    else      out_bf16[(size_t)row * DIM + col] = f32_to_bf16(v);
                }
            }
        }
    }
}

extern "C" void kernel_launch(void* const* d_in, const int* in_sizes, int n_in,
                              void* d_out, int out_size, void* d_ws, size_t ws_size,
                              hipStream_t stream) {
    const float* x0  = (const float*)d_in[0];
    const int*   ei  = (const int*)d_in[1];
    const float* W   = (const float*)d_in[2];
    float*       out = (float*)d_out;

    const int N = in_sizes[0] / DIM;
    const int E = in_sizes[1] / 2;
    const int N_pad = (N + 63) & ~63;
    const int* src = ei;
    const int* dst = ei + E;

    const int nb = (N + 1 + SCAN_B - 1) / SCAN_B;

    char* ws = (char*)d_ws;
    size_t off = 0;
    auto alloc = [&](size_t bytes) { char* p = ws + off; off += (bytes + 15) & ~size_t(15); return p; };
    unsigned short* act_a   = (unsigned short*)alloc((size_t)N_pad * DIM * 2);
    unsigned short* act_b   = (unsigned short*)alloc((size_t)N_pad * DIM * 2);
    unsigned short* x0b     = (unsigned short*)alloc((size_t)N_pad * DIM * 2);
    unsigned short* Wt      = (unsigned short*)alloc((size_t)DIM * DIM * 2);
    float* inv_deg  = (float*)alloc((size_t)N * 4);
    int*   deg      = (int*)  alloc((size_t)N * 4 * 2);   // deg + cursor, adjacent
    int*   cursor   = deg + N;
    int*   row_start= (int*)  alloc((size_t)(N + 1) * 4);
    int*   excl     = (int*)  alloc((size_t)(N + 1) * 4);
    int*   bsums    = (int*)  alloc((size_t)nb * 4);
    int*   csr_src  = (int*)  alloc((size_t)E * 4);

    // ---- CSR build + W/x0 prep (per launch) ----
    hipMemsetAsync(deg, 0, (size_t)N * 4 * 2, stream);
    deg_kernel<<<(E + 255) / 256, 256, 0, stream>>>(dst, E, deg);
    scan1_kernel<<<nb, SCAN_B, 0, stream>>>(deg, N, excl, bsums);
    scan2_kernel<<<1, SCAN_B, 0, stream>>>(bsums, nb);
    scan3_kernel<<<nb, SCAN_B, 0, stream>>>(excl, bsums, deg, N, row_start, inv_deg);
    fill_kernel<<<(E + 255) / 256, 256, 0, stream>>>(src, dst, E, row_start, cursor, csr_src);
    const int n4 = N * DIM / 4;
    prep_kernel<<<DIM + (n4 + 255) / 256, 256, 0, stream>>>(W, Wt, x0, x0b, n4);

    // ---- 5 fused GCN layers: x0b -> a -> b -> a -> b -> out ----
    const int grid = N_pad / 64;
    layer_kernel<false><<<grid, 256, 0, stream>>>(x0b,   x0b, row_start, csr_src, inv_deg, Wt, nullptr, act_a, N);
    layer_kernel<false><<<grid, 256, 0, stream>>>(act_a, x0b, row_start, csr_src, inv_deg, Wt, nullptr, act_b, N);
    layer_kernel<false><<<grid, 256, 0, stream>>>(act_b, x0b, row_start, csr_src, inv_deg, Wt, nullptr, act_a, N);
    layer_kernel<false><<<grid, 256, 0, stream>>>(act_a, x0b, row_start, csr_src, inv_deg, Wt, nullptr, act_b, N);
    layer_kernel<true ><<<grid, 256, 0, stream>>>(act_b, x0b, row_start, csr_src, inv_deg, Wt, out, nullptr, N);
}